// Round 1
// baseline (495.928 us; speedup 1.0000x reference)
//
#include <hip/hip_runtime.h>
#include <math.h>

#define BH 131072  // B*H = 256*512

// ---------------- Kernel A: six projections ----------------
// out[b, n] = sum_d x[b,d] * Wstack[n, d],  n in [0, 3072)
// mat = n>>9 selects W_q..W_o; mats 3,4,5 get bias + sigmoid.
// Tiles: BM=64 (batch), BN=64 (n), BK=16. 256 threads, 4x4 micro-tile.
__global__ __launch_bounds__(256) void proj_gemm(
    const float* __restrict__ x,
    const float* __restrict__ Wq, const float* __restrict__ Wk,
    const float* __restrict__ Wv, const float* __restrict__ Wi,
    const float* __restrict__ Wf, const float* __restrict__ Wo,
    const float* __restrict__ bi, const float* __restrict__ bf,
    const float* __restrict__ bo,
    float* __restrict__ ws)
{
    __shared__ float As[16][64];  // [k][m]
    __shared__ float Bs[16][64];  // [k][n]

    const int t  = threadIdx.x;
    const int tx = t & 15;        // n-dir
    const int ty = t >> 4;        // m-dir
    const int n0 = blockIdx.x * 64;
    const int m0 = blockIdx.y * 64;
    const int mat = n0 >> 9;      // 64 | 512, so a tile never spans matrices
    const int hn0 = n0 & 511;

    const float* W;
    switch (mat) {
        case 0: W = Wq; break; case 1: W = Wk; break; case 2: W = Wv; break;
        case 3: W = Wi; break; case 4: W = Wf; break; default: W = Wo; break;
    }

    const int lr = t >> 2;         // 0..63 : row within tile
    const int lk = (t & 3) * 4;    // 0,4,8,12 : k within chunk
    const float* xg = &x[(m0 + lr) * 512 + lk];
    const float* wg = &W[(hn0 + lr) * 512 + lk];

    float4 xa = *(const float4*)xg;   // prefetch chunk 0
    float4 wa = *(const float4*)wg;

    float acc[4][4];
#pragma unroll
    for (int i = 0; i < 4; i++)
#pragma unroll
        for (int j = 0; j < 4; j++) acc[i][j] = 0.f;

    for (int k0 = 0; k0 < 512; k0 += 16) {
        As[lk + 0][lr] = xa.x; As[lk + 1][lr] = xa.y;
        As[lk + 2][lr] = xa.z; As[lk + 3][lr] = xa.w;
        Bs[lk + 0][lr] = wa.x; Bs[lk + 1][lr] = wa.y;
        Bs[lk + 2][lr] = wa.z; Bs[lk + 3][lr] = wa.w;
        __syncthreads();
        if (k0 + 16 < 512) {  // register prefetch of next chunk (hide HBM latency)
            xa = *(const float4*)(xg + k0 + 16);
            wa = *(const float4*)(wg + k0 + 16);
        }
#pragma unroll
        for (int kk = 0; kk < 16; kk++) {
            float4 a4 = *(const float4*)&As[kk][ty * 4];
            float4 b4 = *(const float4*)&Bs[kk][tx * 4];
            float a[4] = {a4.x, a4.y, a4.z, a4.w};
            float b[4] = {b4.x, b4.y, b4.z, b4.w};
#pragma unroll
            for (int i = 0; i < 4; i++)
#pragma unroll
                for (int j = 0; j < 4; j++) acc[i][j] += a[i] * b[j];
        }
        __syncthreads();
    }

    // Epilogue: bias + sigmoid for i/f/o, vectorized store to workspace.
    const float* bias = (mat == 3) ? bi : (mat == 4) ? bf : (mat == 5) ? bo : nullptr;
    float bv[4] = {0.f, 0.f, 0.f, 0.f};
    if (bias) {
#pragma unroll
        for (int j = 0; j < 4; j++) bv[j] = bias[hn0 + tx * 4 + j];
    }
#pragma unroll
    for (int i = 0; i < 4; i++) {
        const int b = m0 + ty * 4 + i;
        float4 o;
        float r[4];
#pragma unroll
        for (int j = 0; j < 4; j++) {
            float vv = acc[i][j];
            if (bias) vv = 1.f / (1.f + expf(-(vv + bv[j])));
            r[j] = vv;
        }
        o.x = r[0]; o.y = r[1]; o.z = r[2]; o.w = r[3];
        *(float4*)&ws[(size_t)mat * BH + b * 512 + hn0 + tx * 4] = o;
    }
}

// ---------------- Kernel B: fused state update + readout ----------------
// C_t[b,i,:] = f[b,i]*C_prev[b,i,:] + (i[b,i]*k[b,i])*v[b,:]
// h[b,i]     = o[b,i] * tanh( dot(C_t[b,i,:], q[b,:]) )
// One wave per row; v and q staged in LDS per block; 32 rows/block.
#define ROWS 32
__global__ __launch_bounds__(256) void update_kernel(
    const float* __restrict__ Cprev,
    const float* __restrict__ ws,
    float* __restrict__ hout,
    float* __restrict__ Cout)
{
    const int b    = blockIdx.x;   // 0..255
    const int rblk = blockIdx.y;   // 0..15

    __shared__ float vq[1024];     // v[0..511], q[512..1023]

    const float* qv = ws + 0 * (size_t)BH + b * 512;
    const float* kv = ws + 1 * (size_t)BH + b * 512;
    const float* vv = ws + 2 * (size_t)BH + b * 512;
    const float* ig = ws + 3 * (size_t)BH + b * 512;
    const float* fg = ws + 4 * (size_t)BH + b * 512;
    const float* og = ws + 5 * (size_t)BH + b * 512;

    const int t = threadIdx.x;
    ((float4*)vq)[t] = (t < 128) ? ((const float4*)vv)[t]
                                 : ((const float4*)qv)[t - 128];
    __syncthreads();

    const int wave = t >> 6;
    const int lane = t & 63;

    const float4 v0 = ((const float4*)vq)[lane];
    const float4 v1 = ((const float4*)vq)[64 + lane];
    const float4 q0 = ((const float4*)(vq + 512))[lane];
    const float4 q1 = ((const float4*)(vq + 512))[64 + lane];

    for (int rr = wave; rr < ROWS; rr += 4) {
        const int row = rblk * ROWS + rr;
        const float fv  = fg[row];
        const float ikv = ig[row] * kv[row];
        const float ov  = og[row];

        const size_t roff = ((size_t)b * 512 + row) * 512;
        const float4* cin  = (const float4*)(Cprev + roff);
        float4*       cout = (float4*)(Cout + roff);

        float4 c0 = cin[lane];
        float4 c1 = cin[64 + lane];

        float4 o0, o1;
        o0.x = fv * c0.x + ikv * v0.x;  o0.y = fv * c0.y + ikv * v0.y;
        o0.z = fv * c0.z + ikv * v0.z;  o0.w = fv * c0.w + ikv * v0.w;
        o1.x = fv * c1.x + ikv * v1.x;  o1.y = fv * c1.y + ikv * v1.y;
        o1.z = fv * c1.z + ikv * v1.z;  o1.w = fv * c1.w + ikv * v1.w;

        cout[lane]      = o0;
        cout[64 + lane] = o1;

        float dot = o0.x * q0.x + o0.y * q0.y + o0.z * q0.z + o0.w * q0.w
                  + o1.x * q1.x + o1.y * q1.y + o1.z * q1.z + o1.w * q1.w;
#pragma unroll
        for (int off = 32; off > 0; off >>= 1)
            dot += __shfl_down(dot, off, 64);

        if (lane == 0) hout[b * 512 + row] = ov * tanhf(dot);
    }
}

extern "C" void kernel_launch(void* const* d_in, const int* in_sizes, int n_in,
                              void* d_out, int out_size, void* d_ws, size_t ws_size,
                              hipStream_t stream) {
    const float* x     = (const float*)d_in[0];
    // d_in[1] = h_prev (unused by the reference)
    const float* Cprev = (const float*)d_in[2];
    const float* Wq    = (const float*)d_in[3];
    const float* Wk    = (const float*)d_in[4];
    const float* Wv    = (const float*)d_in[5];
    const float* Wi    = (const float*)d_in[6];
    const float* Wf    = (const float*)d_in[7];
    const float* Wo    = (const float*)d_in[8];
    const float* bi    = (const float*)d_in[9];
    const float* bf    = (const float*)d_in[10];
    const float* bo    = (const float*)d_in[11];

    float* ws   = (float*)d_ws;
    float* hout = (float*)d_out;          // h_t: BH floats
    float* Cout = hout + BH;              // C_t: B*H*H floats

    proj_gemm<<<dim3(48, 4), 256, 0, stream>>>(x, Wq, Wk, Wv, Wi, Wf, Wo,
                                               bi, bf, bo, ws);
    update_kernel<<<dim3(256, 16), 256, 0, stream>>>(Cprev, ws, hout, Cout);
}

// Round 2
// 477.562 us; speedup vs baseline: 1.0385x; 1.0385x over previous
//
#include <hip/hip_runtime.h>
#include <math.h>

#define BH 131072  // B*H = 256*512

typedef float f4v __attribute__((ext_vector_type(4)));

// ---------------- Kernel A: six projections ----------------
// out[b, n] = sum_d x[b,d] * Wstack[n, d],  n in [0, 3072)
// mat = n>>9 selects W_q..W_o; mats 3,4,5 get bias + sigmoid.
// Tiles: BM=64 (batch), BN=64 (n), BK=16. 256 threads, 4x4 micro-tile.
__global__ __launch_bounds__(256) void proj_gemm(
    const float* __restrict__ x,
    const float* __restrict__ Wq, const float* __restrict__ Wk,
    const float* __restrict__ Wv, const float* __restrict__ Wi,
    const float* __restrict__ Wf, const float* __restrict__ Wo,
    const float* __restrict__ bi, const float* __restrict__ bf,
    const float* __restrict__ bo,
    float* __restrict__ ws)
{
    __shared__ float As[16][64];  // [k][m]
    __shared__ float Bs[16][64];  // [k][n]

    const int t  = threadIdx.x;
    const int tx = t & 15;        // n-dir
    const int ty = t >> 4;        // m-dir
    const int n0 = blockIdx.x * 64;
    const int m0 = blockIdx.y * 64;
    const int mat = n0 >> 9;      // 64 | 512, so a tile never spans matrices
    const int hn0 = n0 & 511;

    const float* W;
    switch (mat) {
        case 0: W = Wq; break; case 1: W = Wk; break; case 2: W = Wv; break;
        case 3: W = Wi; break; case 4: W = Wf; break; default: W = Wo; break;
    }

    const int lr = t >> 2;         // 0..63 : row within tile
    const int lk = (t & 3) * 4;    // 0,4,8,12 : k within chunk
    const float* xg = &x[(m0 + lr) * 512 + lk];
    const float* wg = &W[(hn0 + lr) * 512 + lk];

    float4 xa = *(const float4*)xg;   // prefetch chunk 0
    float4 wa = *(const float4*)wg;

    float acc[4][4];
#pragma unroll
    for (int i = 0; i < 4; i++)
#pragma unroll
        for (int j = 0; j < 4; j++) acc[i][j] = 0.f;

    for (int k0 = 0; k0 < 512; k0 += 16) {
        As[lk + 0][lr] = xa.x; As[lk + 1][lr] = xa.y;
        As[lk + 2][lr] = xa.z; As[lk + 3][lr] = xa.w;
        Bs[lk + 0][lr] = wa.x; Bs[lk + 1][lr] = wa.y;
        Bs[lk + 2][lr] = wa.z; Bs[lk + 3][lr] = wa.w;
        __syncthreads();
        if (k0 + 16 < 512) {  // register prefetch of next chunk (hide HBM latency)
            xa = *(const float4*)(xg + k0 + 16);
            wa = *(const float4*)(wg + k0 + 16);
        }
#pragma unroll
        for (int kk = 0; kk < 16; kk++) {
            float4 a4 = *(const float4*)&As[kk][ty * 4];
            float4 b4 = *(const float4*)&Bs[kk][tx * 4];
            float a[4] = {a4.x, a4.y, a4.z, a4.w};
            float b[4] = {b4.x, b4.y, b4.z, b4.w};
#pragma unroll
            for (int i = 0; i < 4; i++)
#pragma unroll
                for (int j = 0; j < 4; j++) acc[i][j] += a[i] * b[j];
        }
        __syncthreads();
    }

    // Epilogue: bias + sigmoid for i/f/o, vectorized store to workspace.
    const float* bias = (mat == 3) ? bi : (mat == 4) ? bf : (mat == 5) ? bo : nullptr;
    float bv[4] = {0.f, 0.f, 0.f, 0.f};
    if (bias) {
#pragma unroll
        for (int j = 0; j < 4; j++) bv[j] = bias[hn0 + tx * 4 + j];
    }
#pragma unroll
    for (int i = 0; i < 4; i++) {
        const int b = m0 + ty * 4 + i;
        float4 o;
        float r[4];
#pragma unroll
        for (int j = 0; j < 4; j++) {
            float vv = acc[i][j];
            if (bias) vv = 1.f / (1.f + expf(-(vv + bv[j])));
            r[j] = vv;
        }
        o.x = r[0]; o.y = r[1]; o.z = r[2]; o.w = r[3];
        *(float4*)&ws[(size_t)mat * BH + b * 512 + hn0 + tx * 4] = o;
    }
}

// ---------------- Kernel B: fused state update + readout ----------------
// C_t[b,i,:] = f[b,i]*C_prev[b,i,:] + (i[b,i]*k[b,i])*v[b,:]
// h[b,i]     = o[b,i] * tanh( dot(C_t[b,i,:], q[b,:]) )
// One wave per row, TWO rows in flight per wave for MLP; v,q staged in LDS.
// Nontemporal hints on the 512 MB C streams (no reuse; keep L2 for v/q).
#define ROWS 32
__global__ __launch_bounds__(256) void update_kernel(
    const float* __restrict__ Cprev,
    const float* __restrict__ ws,
    float* __restrict__ hout,
    float* __restrict__ Cout)
{
    const int rblk = blockIdx.x;   // 0..15  (adjacent blocks share b -> L2 reuse of v/q)
    const int b    = blockIdx.y;   // 0..255

    __shared__ float vq[1024];     // v[0..511], q[512..1023]

    const float* qv = ws + 0 * (size_t)BH + b * 512;
    const float* kv = ws + 1 * (size_t)BH + b * 512;
    const float* vv = ws + 2 * (size_t)BH + b * 512;
    const float* ig = ws + 3 * (size_t)BH + b * 512;
    const float* fg = ws + 4 * (size_t)BH + b * 512;
    const float* og = ws + 5 * (size_t)BH + b * 512;

    const int t = threadIdx.x;
    ((float4*)vq)[t] = (t < 128) ? ((const float4*)vv)[t]
                                 : ((const float4*)qv)[t - 128];
    __syncthreads();

    const int wave = t >> 6;
    const int lane = t & 63;

    const f4v v0 = ((const f4v*)vq)[lane];
    const f4v v1 = ((const f4v*)vq)[64 + lane];
    const f4v q0 = ((const f4v*)(vq + 512))[lane];
    const f4v q1 = ((const f4v*)(vq + 512))[64 + lane];

    // 4 iterations, 2 rows per iteration per wave (rows rr and rr+4)
#pragma unroll
    for (int it = 0; it < 4; it++) {
        const int rA = rblk * ROWS + wave + it * 8;
        const int rB = rA + 4;

        const size_t offA = ((size_t)b * 512 + rA) * 512;
        const size_t offB = ((size_t)b * 512 + rB) * 512;
        const f4v* cinA = (const f4v*)(Cprev + offA);
        const f4v* cinB = (const f4v*)(Cprev + offB);
        f4v* coutA = (f4v*)(Cout + offA);
        f4v* coutB = (f4v*)(Cout + offB);

        // issue all four loads up front (64 B/lane in flight)
        f4v a0 = __builtin_nontemporal_load(cinA + lane);
        f4v a1 = __builtin_nontemporal_load(cinA + 64 + lane);
        f4v b0 = __builtin_nontemporal_load(cinB + lane);
        f4v b1 = __builtin_nontemporal_load(cinB + 64 + lane);

        const float fA  = fg[rA];
        const float ikA = ig[rA] * kv[rA];
        const float oA  = og[rA];
        const float fB  = fg[rB];
        const float ikB = ig[rB] * kv[rB];
        const float oB  = og[rB];

        f4v nA0 = fA * a0 + ikA * v0;
        f4v nA1 = fA * a1 + ikA * v1;
        f4v nB0 = fB * b0 + ikB * v0;
        f4v nB1 = fB * b1 + ikB * v1;

        __builtin_nontemporal_store(nA0, coutA + lane);
        __builtin_nontemporal_store(nA1, coutA + 64 + lane);
        __builtin_nontemporal_store(nB0, coutB + lane);
        __builtin_nontemporal_store(nB1, coutB + 64 + lane);

        f4v pA = nA0 * q0 + nA1 * q1;
        f4v pB = nB0 * q0 + nB1 * q1;
        float dA = pA.x + pA.y + pA.z + pA.w;
        float dB = pB.x + pB.y + pB.z + pB.w;

        // two independent shuffle-reduce chains, interleaved
#pragma unroll
        for (int off = 32; off > 0; off >>= 1) {
            dA += __shfl_down(dA, off, 64);
            dB += __shfl_down(dB, off, 64);
        }

        if (lane == 0) {
            hout[b * 512 + rA] = oA * tanhf(dA);
            hout[b * 512 + rB] = oB * tanhf(dB);
        }
    }
}

extern "C" void kernel_launch(void* const* d_in, const int* in_sizes, int n_in,
                              void* d_out, int out_size, void* d_ws, size_t ws_size,
                              hipStream_t stream) {
    const float* x     = (const float*)d_in[0];
    // d_in[1] = h_prev (unused by the reference)
    const float* Cprev = (const float*)d_in[2];
    const float* Wq    = (const float*)d_in[3];
    const float* Wk    = (const float*)d_in[4];
    const float* Wv    = (const float*)d_in[5];
    const float* Wi    = (const float*)d_in[6];
    const float* Wf    = (const float*)d_in[7];
    const float* Wo    = (const float*)d_in[8];
    const float* bi    = (const float*)d_in[9];
    const float* bf    = (const float*)d_in[10];
    const float* bo    = (const float*)d_in[11];

    float* ws   = (float*)d_ws;
    float* hout = (float*)d_out;          // h_t: BH floats
    float* Cout = hout + BH;              // C_t: B*H*H floats

    proj_gemm<<<dim3(48, 4), 256, 0, stream>>>(x, Wq, Wk, Wv, Wi, Wf, Wo,
                                               bi, bf, bo, ws);
    update_kernel<<<dim3(16, 256), 256, 0, stream>>>(Cprev, ws, hout, Cout);
}